// Round 1
// baseline (621.167 us; speedup 1.0000x reference)
//
#include <hip/hip_runtime.h>
#include <stdint.h>

typedef unsigned short u16;
typedef __attribute__((ext_vector_type(8))) short s8v;    // 8 x bf16
typedef __attribute__((ext_vector_type(4))) float f4v;    // 4 x f32
typedef __fp16 h2v __attribute__((ext_vector_type(2)));   // 2 x f16

__device__ __forceinline__ float bu2f(u16 u) {
  return __uint_as_float(((uint32_t)u) << 16);
}
__device__ __forceinline__ u16 f2bu(float f) {
  uint32_t u = __float_as_uint(f);
  u += 0x7fffu + ((u >> 16) & 1u);  // RNE
  return (u16)(u >> 16);
}

union U32H2 { uint32_t u; h2v h; };

__device__ __forceinline__ uint32_t pk2h(float a, float b) {
  U32H2 x;
  x.h = __builtin_amdgcn_cvt_pkrtz(a, b);  // exact for bf16-valued inputs
  return x.u;
}

// R1: force hardware v_dot2_f32_f16 (VOP3P, 2 f16 MACs + f32 accum per inst).
// Theory: __has_builtin(__builtin_amdgcn_fdot2) was false on gfx950 (clang
// feature gate), so the scalar cvt+fma fallback ran -> ~3x VALU inflation
// (measured 2.4e8 VALU inst vs 7.6e7 dot2 needed). Inline asm removes the
// ambiguity about what was compiled.
__device__ __forceinline__ float fdot2u(uint32_t a, uint32_t b, float c) {
  float d;
  asm("v_dot2_f32_f16 %0, %1, %2, %3" : "=v"(d) : "v"(a), "v"(b), "v"(c));
  return d;
}

// ---- input dtype abstraction ----------------------------------------------
template <bool F32> struct In;
template <> struct In<true> {
  static __device__ __forceinline__ float ld(const void* p, long i) {
    return ((const float*)p)[i];
  }
};
template <> struct In<false> {
  static __device__ __forceinline__ float ld(const void* p, long i) {
    return bu2f(((const u16*)p)[i]);
  }
};

// ---- dtype detector (proven) ----------------------------------------------
__global__ void k_detect(const u16* __restrict__ x, int* __restrict__ flag) {
  __shared__ int s[64];
  int cnt = 0;
  for (int i = threadIdx.x; i < 2048; i += 64) {
    int e = (x[i] >> 7) & 0xFF;
    cnt += (e >= 96 && e <= 134) ? 1 : 0;
  }
  s[threadIdx.x] = cnt;
  __syncthreads();
  if (threadIdx.x == 0) {
    int t = 0;
    for (int i = 0; i < 64; ++i) t += s[i];
    *flag = (t >= 1843) ? 0 : 1;  // 0 = bf16, 1 = f32
  }
}

// ---------------------------------------------------------------------------
// Weight transforms into ws:
//  fc1t [128][416] bf16, fc2t [96][128] bf16, w1t [2][2048][96] bf16,
//  w2t [2][96][2048] bf16, cdw: f16-pair packed conv weights + f32 biases.
// ---------------------------------------------------------------------------
__device__ __forceinline__ u16 f2h16(float f) {
  __fp16 h = (__fp16)f;
  u16 r;
  __builtin_memcpy(&r, &h, 2);
  return r;
}

template <bool INF32>
__global__ __launch_bounds__(256) void k_trans(
    const int* __restrict__ flag,
    const void* __restrict__ fc1w, const void* __restrict__ fc2w,
    const void* __restrict__ ew1, const void* __restrict__ ew2,
    const void* __restrict__ c1w, const void* __restrict__ c1b,
    const void* __restrict__ c2w, const void* __restrict__ c2b,
    u16* __restrict__ fc1t, u16* __restrict__ fc2t,
    u16* __restrict__ w1t, u16* __restrict__ w2t,
    uint32_t* __restrict__ cdw) {
  if (*flag != (INF32 ? 1 : 0)) return;
  long gid = (long)blockIdx.x * 256 + threadIdx.x;
  if (gid < 53248) {                       // fc1t: [128 n][416 k]
    int n = (int)(gid / 416), k = (int)(gid % 416);
    fc1t[gid] = (n < 120 && k < 400) ? f2bu(In<INF32>::ld(fc1w, (long)k * 120 + n)) : (u16)0;
  } else if (gid < 65536) {                // fc2t: [96 n][128 k]
    long i = gid - 53248;
    int n = (int)(i / 128), k = (int)(i % 128);
    fc2t[i] = (n < 84 && k < 120) ? f2bu(In<INF32>::ld(fc2w, (long)k * 84 + n)) : (u16)0;
  } else if (gid < 458752) {               // w1t: [2][2048 n][96 k]
    long i = gid - 65536;
    int e = (int)(i / 196608);
    long r = i % 196608;
    int n = (int)(r / 96), k = (int)(r % 96);
    w1t[i] = (k < 84) ? f2bu(In<INF32>::ld(ew1, ((long)e * 84 + k) * 2048 + n)) : (u16)0;
  } else if (gid < 851968) {               // w2t: [2][96 n][2048 k]
    long i = gid - 458752;
    int e = (int)(i / 196608);
    long r = i % 196608;
    int n = (int)(r / 2048), k = (int)(r % 2048);
    w2t[i] = (n < 84) ? f2bu(In<INF32>::ld(ew2, ((long)e * 2048 + k) * 84 + n)) : (u16)0;
  } else if (gid < 853700) {               // conv f16-pair weights + biases
    long i = gid - 851968;
    if (i < 270) {            // cd1: [6c][3ic][5ky][3p]
      int p = (int)(i % 3), ky = (int)((i / 3) % 5);
      int ic = (int)((i / 15) % 3), c = (int)(i / 45);
      long base = (((long)c * 3 + ic) * 5 + ky) * 5;
      float w0 = In<INF32>::ld(c1w, base + 2 * p);
      float w1 = (2 * p + 1 < 5) ? In<INF32>::ld(c1w, base + 2 * p + 1) : 0.f;
      cdw[i] = (uint32_t)f2h16(w0) | ((uint32_t)f2h16(w1) << 16);
    } else if (i < 1710) {    // cd2: [16c][6ic][5ky][3p]
      long j = i - 270;
      int p = (int)(j % 3), ky = (int)((j / 3) % 5);
      int ic = (int)((j / 15) % 6), c = (int)(j / 90);
      long base = (((long)c * 6 + ic) * 5 + ky) * 5;
      float w0 = In<INF32>::ld(c2w, base + 2 * p);
      float w1 = (2 * p + 1 < 5) ? In<INF32>::ld(c2w, base + 2 * p + 1) : 0.f;
      cdw[270 + j] = (uint32_t)f2h16(w0) | ((uint32_t)f2h16(w1) << 16);
    } else if (i < 1716) {    // cb1 (f32)
      ((float*)(cdw + 1710))[i - 1710] = In<INF32>::ld(c1b, i - 1710);
    } else if (i < 1732) {    // cb2 (f32)
      ((float*)(cdw + 1716))[i - 1716] = In<INF32>::ld(c2b, i - 1716);
    }
  }
}

// ---------------------------------------------------------------------------
// Conv kernel v3: f16 LDS + v_dot2_f32_f16 (2 MACs/inst, f32 accumulate).
// 5 images/block; aligned window dwords direct, shifted via alignbit.
// Out p2: [B][416] bf16, cols 400..415 zero.
// ---------------------------------------------------------------------------
#define CIMG 5
template <bool INF32>
__global__ __launch_bounds__(256) void k_conv(
    const int* __restrict__ flag,
    const void* __restrict__ x,
    const uint32_t* __restrict__ cdw,
    u16* __restrict__ p2, int Btot) {
  if (*flag != (INF32 ? 1 : 0)) return;
  __shared__ u16 sxh[CIMG * 3 * 32 * 36];   // f16, 34,560 B
  __shared__ u16 sp1h[CIMG * 6 * 14 * 18];  // f16, 15,120 B
  const uint32_t* cd1 = cdw;
  const uint32_t* cd2 = cdw + 270;
  const float* cb1 = (const float*)(cdw + 1710);
  const float* cb2 = (const float*)(cdw + 1716);
  const int tid = threadIdx.x;
  const long gimg0 = (long)blockIdx.x * CIMG;

  // zero pad columns (sxh cols 32..35, sp1h cols 14..17)
  for (int r = tid; r < CIMG * 96; r += 256) {
    *(uint32_t*)(sxh + (size_t)r * 36 + 32) = 0;
    *(uint32_t*)(sxh + (size_t)r * 36 + 34) = 0;
  }
  for (int r = tid; r < CIMG * 84; r += 256) {
    *(uint32_t*)(sp1h + (size_t)r * 18 + 14) = 0;
    *(uint32_t*)(sp1h + (size_t)r * 18 + 16) = 0;
  }

  // stage x -> f16 LDS
  for (int i = tid; i < CIMG * 96; i += 256) {
    int img = i / 96, rem = i - img * 96;
    if (gimg0 + img < Btot) {
      long goff = (gimg0 + img) * 3072 + (long)rem * 32;
      u16* dst = sxh + (size_t)i * 36;
      if (!INF32) {
        const uint32_t* src = (const uint32_t*)((const u16*)x + goff);
#pragma unroll
        for (int j = 0; j < 16; ++j) {
          uint32_t d = src[j];
          *(uint32_t*)(dst + 2 * j) =
              pk2h(__uint_as_float(d << 16), __uint_as_float(d & 0xffff0000u));
        }
      } else {
        const float* src = (const float*)x + goff;
#pragma unroll
        for (int j = 0; j < 16; ++j)
          *(uint32_t*)(dst + 2 * j) = pk2h(src[2 * j], src[2 * j + 1]);
      }
    }
  }
  __syncthreads();

  // conv1 + relu + pool: task = (img, pooled pos), all 6 channels
  for (int task = tid; task < CIMG * 196; task += 256) {
    int img = task / 196, pos = task - img * 196;
    if (gimg0 + img >= Btot) continue;
    int py = pos / 14, px = pos - py * 14;
    int x0 = 2 * px, y0 = 2 * py;
    float acc[6][4];
#pragma unroll
    for (int c = 0; c < 6; ++c) {
      float bv = cb1[c];
      acc[c][0] = bv; acc[c][1] = bv; acc[c][2] = bv; acc[c][3] = bv;
    }
    for (int ic = 0; ic < 3; ++ic) {
      uint32_t A[6][4], S[6][3];
      const u16* rb = sxh + ((size_t)(img * 3 + ic) * 32 + y0) * 36 + x0;
#pragma unroll
      for (int r = 0; r < 6; ++r) {
#pragma unroll
        for (int p = 0; p < 4; ++p)
          A[r][p] = *(const uint32_t*)(rb + (size_t)r * 36 + 2 * p);
#pragma unroll
        for (int p = 0; p < 3; ++p)
          S[r][p] = (A[r][p] >> 16) | (A[r][p + 1] << 16);
      }
#pragma unroll
      for (int c = 0; c < 6; ++c) {
        const uint32_t* wb = cd1 + ((c * 3 + ic) * 5) * 3;
#pragma unroll
        for (int ky = 0; ky < 5; ++ky) {
#pragma unroll
          for (int p = 0; p < 3; ++p) {
            uint32_t w = wb[ky * 3 + p];
            acc[c][0] = fdot2u(A[ky][p], w, acc[c][0]);
            acc[c][1] = fdot2u(S[ky][p], w, acc[c][1]);
            acc[c][2] = fdot2u(A[ky + 1][p], w, acc[c][2]);
            acc[c][3] = fdot2u(S[ky + 1][p], w, acc[c][3]);
          }
        }
      }
    }
#pragma unroll
    for (int c = 0; c < 6; ++c) {
      float m = fmaxf(0.f, fmaxf(fmaxf(acc[c][0], acc[c][1]),
                                 fmaxf(acc[c][2], acc[c][3])));
      sp1h[((size_t)(img * 6 + c) * 14 + py) * 18 + px] = f2h16(m);
    }
  }
  __syncthreads();

  // conv2 + relu + pool: task = (img, 4-channel group, pooled pos)
  for (int task = tid; task < CIMG * 100; task += 256) {
    int img = task / 100, r0 = task - img * 100;
    if (gimg0 + img >= Btot) continue;
    int grp = r0 / 25, pos = r0 - grp * 25;
    int py = pos / 5, px = pos - py * 5;
    int x0 = 2 * px, y0 = 2 * py;
    int c0 = grp * 4;
    float acc[4][4];
#pragma unroll
    for (int c = 0; c < 4; ++c) {
      float bv = cb2[c0 + c];
      acc[c][0] = bv; acc[c][1] = bv; acc[c][2] = bv; acc[c][3] = bv;
    }
    for (int ic = 0; ic < 6; ++ic) {
      uint32_t A[6][4], S[6][3];
      const u16* rb = sp1h + ((size_t)(img * 6 + ic) * 14 + y0) * 18 + x0;
#pragma unroll
      for (int r = 0; r < 6; ++r) {
#pragma unroll
        for (int p = 0; p < 4; ++p)
          A[r][p] = *(const uint32_t*)(rb + (size_t)r * 18 + 2 * p);
#pragma unroll
        for (int p = 0; p < 3; ++p)
          S[r][p] = (A[r][p] >> 16) | (A[r][p + 1] << 16);
      }
#pragma unroll
      for (int c = 0; c < 4; ++c) {
        const uint32_t* wb = cd2 + (((c0 + c) * 6 + ic) * 5) * 3;
#pragma unroll
        for (int ky = 0; ky < 5; ++ky) {
#pragma unroll
          for (int p = 0; p < 3; ++p) {
            uint32_t w = wb[ky * 3 + p];
            acc[c][0] = fdot2u(A[ky][p], w, acc[c][0]);
            acc[c][1] = fdot2u(S[ky][p], w, acc[c][1]);
            acc[c][2] = fdot2u(A[ky + 1][p], w, acc[c][2]);
            acc[c][3] = fdot2u(S[ky + 1][p], w, acc[c][3]);
          }
        }
      }
    }
    u16* pout = p2 + (gimg0 + img) * 416;
#pragma unroll
    for (int c = 0; c < 4; ++c) {
      float m = fmaxf(0.f, fmaxf(fmaxf(acc[c][0], acc[c][1]),
                                 fmaxf(acc[c][2], acc[c][3])));
      pout[(c0 + c) * 25 + py * 5 + px] = f2bu(m);
    }
  }

  for (int i = tid; i < CIMG * 16; i += 256) {
    int img = i / 16;
    if (gimg0 + img < Btot) p2[(gimg0 + img) * 416 + 400 + (i & 15)] = 0;
  }
}

// ---------------------------------------------------------------------------
// fcA: fc1 -> fc2 -> gate. 64 tokens/block; writes a2buf [B][104] bf16 +
// scbuf [B][2] f32. MFMA layouts as proven in R3.
// ---------------------------------------------------------------------------
template <bool INF32>
__global__ __launch_bounds__(256) void k_fcA(
    const int* __restrict__ flag,
    const u16* __restrict__ p2,
    const u16* __restrict__ fc1t, const u16* __restrict__ fc2t,
    const void* __restrict__ fc1b, const void* __restrict__ fc2b,
    const void* __restrict__ gw,
    u16* __restrict__ a2buf, float* __restrict__ scbuf) {
  if (*flag != (INF32 ? 1 : 0)) return;
  __shared__ __align__(16) char smem[62976];
  u16* a2s = (u16*)smem;                    // [64][104]
  u16* hs = (u16*)(smem + 13312);           // [64][136]
  u16* wbuf = (u16*)(smem + 31232);
  u16* xs = (u16*)(smem + 57856);           // [64][40]

  const int tid = threadIdx.x;
  const int wv = tid >> 6, ln = tid & 63;
  const int m = ln & 15, quad = ln >> 4;
  const long t0 = (long)blockIdx.x * 64;
  const int row0 = wv * 16 + quad * 4;

  for (int i = tid; i < 30720 / 4; i += 256) ((uint32_t*)smem)[i] = 0;

  // fc1
  f4v acc1[8];
#pragma unroll
  for (int i = 0; i < 8; ++i) acc1[i] = (f4v){0.f, 0.f, 0.f, 0.f};
  for (int s = 0; s < 13; ++s) {
    {
      int r = tid >> 2, c0 = (tid & 3) * 8;
      *(uint4*)(xs + r * 40 + c0) =
          *(const uint4*)(p2 + (t0 + r) * 416 + s * 32 + c0);
      int n = tid >> 1, cw = (tid & 1) * 16;
      *(uint4*)(wbuf + n * 40 + cw) = *(const uint4*)(fc1t + (long)n * 416 + s * 32 + cw);
      *(uint4*)(wbuf + n * 40 + cw + 8) =
          *(const uint4*)(fc1t + (long)n * 416 + s * 32 + cw + 8);
    }
    __syncthreads();
    s8v a = *(const s8v*)(xs + (wv * 16 + m) * 40 + quad * 8);
#pragma unroll
    for (int nt = 0; nt < 8; ++nt) {
      s8v b = *(const s8v*)(wbuf + (nt * 16 + m) * 40 + quad * 8);
      acc1[nt] = __builtin_amdgcn_mfma_f32_16x16x32_bf16(a, b, acc1[nt], 0, 0, 0);
    }
    __syncthreads();
  }
#pragma unroll
  for (int nt = 0; nt < 8; ++nt) {
    int n = nt * 16 + m;
    if (n < 120) {
      float bv = In<INF32>::ld(fc1b, n);
#pragma unroll
      for (int r = 0; r < 4; ++r)
        hs[(row0 + r) * 136 + n] = f2bu(fmaxf(acc1[nt][r] + bv, 0.f));
    }
  }
  __syncthreads();

  // fc2
  for (int i = tid; i < 1536; i += 256) {
    int n = i >> 4, c0 = (i & 15) * 8;
    *(uint4*)(wbuf + n * 136 + c0) = *(const uint4*)(fc2t + n * 128 + c0);
  }
  __syncthreads();
  f4v acc2[6];
#pragma unroll
  for (int i = 0; i < 6; ++i) acc2[i] = (f4v){0.f, 0.f, 0.f, 0.f};
  for (int s = 0; s < 4; ++s) {
    s8v a = *(const s8v*)(hs + (wv * 16 + m) * 136 + s * 32 + quad * 8);
#pragma unroll
    for (int nt = 0; nt < 6; ++nt) {
      s8v b = *(const s8v*)(wbuf + (nt * 16 + m) * 136 + s * 32 + quad * 8);
      acc2[nt] = __builtin_amdgcn_mfma_f32_16x16x32_bf16(a, b, acc2[nt], 0, 0, 0);
    }
  }
  __syncthreads();
#pragma unroll
  for (int nt = 0; nt < 6; ++nt) {
    int n = nt * 16 + m;
    if (n < 84) {
      float bv = In<INF32>::ld(fc2b, n);
#pragma unroll
      for (int r = 0; r < 4; ++r)
        a2s[(row0 + r) * 104 + n] = f2bu(fmaxf(acc2[nt][r] + bv, 0.f));
    }
  }
  __syncthreads();

  // gate + writeback
  if (tid < 64) {
    const u16* xr = a2s + tid * 104;
    float l0 = 0.f, l1 = 0.f;
    for (int k = 0; k < 84; ++k) {
      float xv = bu2f(xr[k]);
      l0 = fmaf(xv, In<INF32>::ld(gw, 2 * k), l0);
      l1 = fmaf(xv, In<INF32>::ld(gw, 2 * k + 1), l1);
    }
    float mx = fmaxf(l0, l1);
    float e0 = __expf(l0 - mx), e1 = __expf(l1 - mx);
    float inv = 1.f / (e0 + e1);
    *(float2*)(scbuf + (t0 + tid) * 2) = make_float2(e0 * inv, e1 * inv);
  }
  for (int i = tid; i < 832; i += 256) {  // 64 rows x 13 uint4
    int r = i / 13, c0 = (i - r * 13) * 8;
    *(uint4*)(a2buf + (t0 + r) * 104 + c0) = *(const uint4*)(a2s + r * 104 + c0);
  }
}

// ---------------------------------------------------------------------------
// exp: one expert per block (grid = [B/64, 2]) -> ybuf [2][B][96] f32.
// ---------------------------------------------------------------------------
template <bool INF32>
__global__ __launch_bounds__(256) void k_exp(
    const int* __restrict__ flag,
    const u16* __restrict__ a2buf, const float* __restrict__ scbuf,
    const u16* __restrict__ w1t, const u16* __restrict__ w2t,
    const void* __restrict__ eb1, const void* __restrict__ eb2,
    float* __restrict__ ybuf, int Btok) {
  if (*flag != (INF32 ? 1 : 0)) return;
  __shared__ __align__(16) char smem[57856];
  u16* a2s = (u16*)smem;                    // [64][104]
  u16* hs = (u16*)(smem + 13312);           // [64][136]
  u16* wbuf = (u16*)(smem + 30720);         // 26,624 B
  float* scs = (float*)(smem + 57344);      // [64]

  const int tid = threadIdx.x;
  const int wv = tid >> 6, ln = tid & 63;
  const int m = ln & 15, quad = ln >> 4;
  const int e = blockIdx.y;
  const long t0 = (long)blockIdx.x * 64;
  const int row0 = wv * 16 + quad * 4;
  const u16* w1te = w1t + (long)e * 196608;
  const u16* w2te = w2t + (long)e * 196608;

  for (int i = tid; i < 832; i += 256) {
    int r = i / 13, c0 = (i - r * 13) * 8;
    *(uint4*)(a2s + r * 104 + c0) = *(const uint4*)(a2buf + (t0 + r) * 104 + c0);
  }
  if (tid < 64) scs[tid] = scbuf[(t0 + tid) * 2 + e];
  __syncthreads();

  f4v acce[6];
#pragma unroll
  for (int i = 0; i < 6; ++i) acce[i] = (f4v){0.f, 0.f, 0.f, 0.f};
  for (int c = 0; c < 16; ++c) {
    const int n0 = c * 128;
    if (c) __syncthreads();
    for (int i = tid; i < 1536; i += 256) {  // wbuf[128][104] <- w1t chunk
      int nl = i / 12, c0 = (i - nl * 12) * 8;
      *(uint4*)(wbuf + nl * 104 + c0) =
          *(const uint4*)(w1te + (long)(n0 + nl) * 96 + c0);
    }
    __syncthreads();
    f4v acch[8];
#pragma unroll
    for (int i = 0; i < 8; ++i) acch[i] = (f4v){0.f, 0.f, 0.f, 0.f};
    for (int s = 0; s < 3; ++s) {
      s8v a = *(const s8v*)(a2s + (wv * 16 + m) * 104 + s * 32 + quad * 8);
#pragma unroll
      for (int nt = 0; nt < 8; ++nt) {
        s8v b = *(const s8v*)(wbuf + (nt * 16 + m) * 104 + s * 32 + quad * 8);
        acch[nt] = __builtin_amdgcn_mfma_f32_16x16x32_bf16(a, b, acch[nt], 0, 0, 0);
      }
    }
#pragma unroll
    for (int nt = 0; nt < 8; ++nt) {
      float bv = In<INF32>::ld(eb1, (long)e * 2048 + n0 + nt * 16 + m);
#pragma unroll
      for (int r = 0; r < 4; ++r)
        hs[(row0 + r) * 136 + nt * 16 + m] = f2bu(fmaxf(acch[nt][r] + bv, 0.f));
    }
    __syncthreads();
    for (int i = tid; i < 1536; i += 256) {  // wbuf[96][136] <- w2t slice
      int n = i >> 4, c0 = (i & 15) * 8;
      *(uint4*)(wbuf + n * 136 + c0) =
          *(const uint4*)(w2te + (long)n * 2048 + n0 + c0);
    }
    __syncthreads();
    for (int s = 0; s < 4; ++s) {
      s8v a = *(const s8v*)(hs + (wv * 16 + m) * 136 + s * 32 + quad * 8);
#pragma unroll
      for (int nt = 0; nt < 6; ++nt) {
        s8v b = *(const s8v*)(wbuf + (nt * 16 + m) * 136 + s * 32 + quad * 8);
        acce[nt] = __builtin_amdgcn_mfma_f32_16x16x32_bf16(a, b, acce[nt], 0, 0, 0);
      }
    }
  }

  // y_e = sc * (acce + b2) -> ybuf
#pragma unroll
  for (int nt = 0; nt < 6; ++nt) {
    int d = nt * 16 + m;
    float bv = (d < 84) ? In<INF32>::ld(eb2, (long)e * 84 + d) : 0.f;
#pragma unroll
    for (int r = 0; r < 4; ++r) {
      float sc = scs[row0 + r];
      ybuf[((size_t)e * Btok + t0 + row0 + r) * 96 + d] = sc * (acce[nt][r] + bv);
    }
  }
}

// ---------------------------------------------------------------------------
// fc3: out = (y0 + y1) @ w3 + b3. 64 tokens/block.
// ---------------------------------------------------------------------------
template <bool INF32>
__global__ __launch_bounds__(256) void k_fc3(
    const int* __restrict__ flag,
    const float* __restrict__ ybuf,
    const void* __restrict__ w3, const void* __restrict__ b3,
    void* __restrict__ out, int Btok) {
  if (*flag != (INF32 ? 1 : 0)) return;
  __shared__ float sw3[840];
  __shared__ float sb3[10];
  const int tid = threadIdx.x;
  const long t0 = (long)blockIdx.x * 64;
  for (int i = tid; i < 840; i += 256) sw3[i] = In<INF32>::ld(w3, i);
  if (tid < 10) sb3[tid] = In<INF32>::ld(b3, tid);
  __syncthreads();
  for (int idx = tid; idx < 640; idx += 256) {
    int tk = idx / 10, cc = idx - tk * 10;
    const float* y0r = ybuf + (t0 + tk) * 96;
    const float* y1r = ybuf + ((size_t)Btok + t0 + tk) * 96;
    float acc = sb3[cc];
    for (int d = 0; d < 84; ++d)
      acc = fmaf(y0r[d] + y1r[d], sw3[d * 10 + cc], acc);
    long oi = (t0 + tk) * 10 + cc;
    if (INF32) ((float*)out)[oi] = acc;
    else ((u16*)out)[oi] = f2bu(acc);
  }
}

// ---------------------------------------------------------------------------
extern "C" void kernel_launch(void* const* d_in, const int* in_sizes, int n_in,
                              void* d_out, int out_size, void* d_ws, size_t ws_size,
                              hipStream_t stream) {
  const int B = in_sizes[0] / 3072;  // 16384
  char* wsb = (char*)d_ws;
  int* flag = (int*)wsb;
  u16* p2 = (u16*)(wsb + 64);                    // [B][416] bf16
  u16* fc1t = p2 + (size_t)B * 416;              // 53,248 elems
  u16* fc2t = fc1t + 53248;                      // 12,288
  u16* w1t = fc2t + 12288;                       // 393,216
  u16* w2t = w1t + 393216;                       // 393,216
  uint32_t* cdw = (uint32_t*)(w2t + 393216);     // 1,732 dwords
  u16* a2buf = (u16*)(cdw + 1732);               // [B][104] bf16
  float* scbuf = (float*)(a2buf + (size_t)B * 104);  // [B][2] f32
  float* ybuf = scbuf + (size_t)B * 2;           // [2][B][96] f32

  k_detect<<<1, 64, 0, stream>>>((const u16*)d_in[0], flag);

  k_trans<false><<<3336, 256, 0, stream>>>(flag, d_in[5], d_in[7], d_in[10],
                                           d_in[12], d_in[1], d_in[2], d_in[3],
                                           d_in[4], fc1t, fc2t, w1t, w2t, cdw);
  k_trans<true><<<3336, 256, 0, stream>>>(flag, d_in[5], d_in[7], d_in[10],
                                          d_in[12], d_in[1], d_in[2], d_in[3],
                                          d_in[4], fc1t, fc2t, w1t, w2t, cdw);

  const int convGrid = (B + CIMG - 1) / CIMG;
  k_conv<false><<<convGrid, 256, 0, stream>>>(flag, d_in[0], cdw, p2, B);
  k_conv<true><<<convGrid, 256, 0, stream>>>(flag, d_in[0], cdw, p2, B);

  k_fcA<false><<<B / 64, 256, 0, stream>>>(flag, p2, fc1t, fc2t, d_in[6],
                                           d_in[8], d_in[9], a2buf, scbuf);
  k_fcA<true><<<B / 64, 256, 0, stream>>>(flag, p2, fc1t, fc2t, d_in[6],
                                          d_in[8], d_in[9], a2buf, scbuf);

  dim3 eg(B / 64, 2);
  k_exp<false><<<eg, 256, 0, stream>>>(flag, a2buf, scbuf, w1t, w2t, d_in[11],
                                       d_in[13], ybuf, B);
  k_exp<true><<<eg, 256, 0, stream>>>(flag, a2buf, scbuf, w1t, w2t, d_in[11],
                                      d_in[13], ybuf, B);

  k_fc3<false><<<B / 64, 256, 0, stream>>>(flag, ybuf, d_in[14], d_in[15],
                                           d_out, B);
  k_fc3<true><<<B / 64, 256, 0, stream>>>(flag, ybuf, d_in[14], d_in[15],
                                          d_out, B);
}

// Round 4
// 557.285 us; speedup vs baseline: 1.1146x; 1.1146x over previous
//
#include <hip/hip_runtime.h>
#include <stdint.h>

typedef unsigned short u16;
typedef __attribute__((ext_vector_type(8))) short s8v;    // 8 x bf16
typedef __attribute__((ext_vector_type(4))) float f4v;    // 4 x f32
typedef __fp16 h2v __attribute__((ext_vector_type(2)));   // 2 x f16
typedef __fp16 h8v __attribute__((ext_vector_type(8)));   // 8 x f16

__device__ __forceinline__ float bu2f(u16 u) {
  return __uint_as_float(((uint32_t)u) << 16);
}
__device__ __forceinline__ u16 f2bu(float f) {
  uint32_t u = __float_as_uint(f);
  u += 0x7fffu + ((u >> 16) & 1u);  // RNE
  return (u16)(u >> 16);
}

union U32H2 { uint32_t u; h2v h; };

__device__ __forceinline__ uint32_t pk2h(float a, float b) {
  U32H2 x;
  x.h = __builtin_amdgcn_cvt_pkrtz(a, b);  // exact for bf16-valued inputs
  return x.u;
}

// ---- input dtype abstraction ----------------------------------------------
template <bool F32> struct In;
template <> struct In<true> {
  static __device__ __forceinline__ float ld(const void* p, long i) {
    return ((const float*)p)[i];
  }
};
template <> struct In<false> {
  static __device__ __forceinline__ float ld(const void* p, long i) {
    return bu2f(((const u16*)p)[i]);
  }
};

// ---- dtype detector (proven) ----------------------------------------------
__global__ void k_detect(const u16* __restrict__ x, int* __restrict__ flag) {
  __shared__ int s[64];
  int cnt = 0;
  for (int i = threadIdx.x; i < 2048; i += 64) {
    int e = (x[i] >> 7) & 0xFF;
    cnt += (e >= 96 && e <= 134) ? 1 : 0;
  }
  s[threadIdx.x] = cnt;
  __syncthreads();
  if (threadIdx.x == 0) {
    int t = 0;
    for (int i = 0; i < 64; ++i) t += s[i];
    *flag = (t >= 1843) ? 0 : 1;  // 0 = bf16, 1 = f32
  }
}

// ---------------------------------------------------------------------------
// Weight transforms into ws:
//  fc1t [128][416] bf16, fc2t [96][128] bf16, w1t [2][2048][96] bf16,
//  w2t [2][96][2048] bf16,
//  cdw: MFMA conv weights: cd1m[3][64][8] f16, cd2m[6][64][8] f16,
//       cb1[6] f32 @dword 2304, cb2[16] f32 @dword 2310. Total 2326 dwords.
// Tap order for conv MFMA (row-padded to 6): t = quad*8 + j,
//   ky = t/6, kxp = t%6; weight 0 for kxp==5 or t>=30 (and n>=6 for conv1).
// ---------------------------------------------------------------------------
__device__ __forceinline__ u16 f2h16(float f) {
  __fp16 h = (__fp16)f;
  u16 r;
  __builtin_memcpy(&r, &h, 2);
  return r;
}

template <bool INF32>
__global__ __launch_bounds__(256) void k_trans(
    const int* __restrict__ flag,
    const void* __restrict__ fc1w, const void* __restrict__ fc2w,
    const void* __restrict__ ew1, const void* __restrict__ ew2,
    const void* __restrict__ c1w, const void* __restrict__ c1b,
    const void* __restrict__ c2w, const void* __restrict__ c2b,
    u16* __restrict__ fc1t, u16* __restrict__ fc2t,
    u16* __restrict__ w1t, u16* __restrict__ w2t,
    uint32_t* __restrict__ cdw) {
  if (*flag != (INF32 ? 1 : 0)) return;
  long gid = (long)blockIdx.x * 256 + threadIdx.x;
  if (gid < 53248) {                       // fc1t: [128 n][416 k]
    int n = (int)(gid / 416), k = (int)(gid % 416);
    fc1t[gid] = (n < 120 && k < 400) ? f2bu(In<INF32>::ld(fc1w, (long)k * 120 + n)) : (u16)0;
  } else if (gid < 65536) {                // fc2t: [96 n][128 k]
    long i = gid - 53248;
    int n = (int)(i / 128), k = (int)(i % 128);
    fc2t[i] = (n < 84 && k < 120) ? f2bu(In<INF32>::ld(fc2w, (long)k * 84 + n)) : (u16)0;
  } else if (gid < 458752) {               // w1t: [2][2048 n][96 k]
    long i = gid - 65536;
    int e = (int)(i / 196608);
    long r = i % 196608;
    int n = (int)(r / 96), k = (int)(r % 96);
    w1t[i] = (k < 84) ? f2bu(In<INF32>::ld(ew1, ((long)e * 84 + k) * 2048 + n)) : (u16)0;
  } else if (gid < 851968) {               // w2t: [2][96 n][2048 k]
    long i = gid - 458752;
    int e = (int)(i / 196608);
    long r = i % 196608;
    int n = (int)(r / 2048), k = (int)(r % 2048);
    w2t[i] = (n < 84) ? f2bu(In<INF32>::ld(ew2, ((long)e * 2048 + k) * 84 + n)) : (u16)0;
  } else if (gid < 856598) {               // conv MFMA weights + biases
    long i = gid - 851968;
    u16* cdh = (u16*)cdw;
    if (i < 1536) {          // cd1m [3 ic][64 lane][8 j]
      int ic = (int)(i >> 9);
      int r = (int)(i & 511);
      int lnn = r >> 3, j = r & 7;
      int n = lnn & 15, qd = lnn >> 4;
      int t = qd * 8 + j, ky = t / 6, kxp = t - ky * 6;
      float v = (n < 6 && t < 30 && kxp < 5)
          ? In<INF32>::ld(c1w, ((long)(n * 3 + ic) * 5 + ky) * 5 + kxp) : 0.f;
      cdh[i] = f2h16(v);
    } else if (i < 4608) {   // cd2m [6 ic][64 lane][8 j]
      long jj = i - 1536;
      int ic = (int)(jj >> 9);
      int r = (int)(jj & 511);
      int lnn = r >> 3, j = r & 7;
      int n = lnn & 15, qd = lnn >> 4;
      int t = qd * 8 + j, ky = t / 6, kxp = t - ky * 6;
      float v = (t < 30 && kxp < 5)
          ? In<INF32>::ld(c2w, ((long)(n * 6 + ic) * 5 + ky) * 5 + kxp) : 0.f;
      cdh[1536 + jj] = f2h16(v);
    } else if (i < 4614) {   // cb1 (f32)
      ((float*)(cdw + 2304))[i - 4608] = In<INF32>::ld(c1b, i - 4608);
    } else if (i < 4630) {   // cb2 (f32)
      ((float*)(cdw + 2310))[i - 4614] = In<INF32>::ld(c2b, i - 4614);
    }
  }
}

// ---------------------------------------------------------------------------
// Conv kernel v4: MFMA implicit-GEMM.
//   M-tile = 16 conv pixels = 4 pooled outs x 2x2 window (pool is in-lane),
//   N = 16 channels, K = 32 per input channel (taps row-padded 5->6).
//   LDS holds a normal and a +1-shifted f16 copy so every A pair-read is an
//   aligned ds_read_b32 (odd window starts hit the shifted copy).
// Out p2: [B][416] bf16, cols 400..415 zero.
// ---------------------------------------------------------------------------
#define CIMG 4
template <bool INF32>
__global__ __launch_bounds__(256) void k_conv(
    const int* __restrict__ flag,
    const void* __restrict__ x,
    const uint32_t* __restrict__ cdw,
    u16* __restrict__ p2, int Btot) {
  if (*flag != (INF32 ? 1 : 0)) return;
  __shared__ __align__(16) u16 sxn[CIMG * 3 * 32 * 36];   // 27,648 B
  __shared__ __align__(16) u16 sxs[CIMG * 3 * 32 * 36];   // shifted: sxs[c]=x[c+1]
  __shared__ __align__(16) u16 sp1n[CIMG * 6 * 14 * 18];  // 12,096 B
  __shared__ __align__(16) u16 sp1s[CIMG * 6 * 14 * 18];
  __shared__ u16 lut1[196];
  __shared__ u16 lut2[32];
  const u16* cdh = (const u16*)cdw;
  const float* cb1f = (const float*)(cdw + 2304);
  const float* cb2f = (const float*)(cdw + 2310);
  const int tid = threadIdx.x;
  const int wv = tid >> 6, ln = tid & 63;
  const int mrow = ln & 15, quad = ln >> 4;
  const long gimg0 = (long)blockIdx.x * CIMG;

  // pooled-pos -> element-offset LUTs
  if (tid < 196) {
    int py = tid / 14, px = tid - py * 14;
    lut1[tid] = (u16)((2 * py) * 36 + 2 * px);
  } else if (tid < 228) {
    int i = tid - 196;
    if (i < 25) {
      int py = i / 5, px = i - py * 5;
      lut2[i] = (u16)((2 * py) * 18 + 2 * px);
    }
  }
  // zero sp1s elts 12,13 of each row (elt13 = orig col14 pad, read by conv2)
  for (int r = tid; r < CIMG * 6 * 14; r += 256)
    *(uint32_t*)(sp1s + (size_t)r * 18 + 12) = 0;

  // stage x -> f16 LDS (normal + shifted copies)
  for (int i = tid; i < CIMG * 96; i += 256) {
    int img = i / 96;
    if (gimg0 + img >= Btot) continue;
    int rem = i - img * 96;
    long goff = (gimg0 + img) * 3072 + (long)rem * 32;
    uint32_t e[17];
    if (!INF32) {
      const uint32_t* src = (const uint32_t*)((const u16*)x + goff);
#pragma unroll
      for (int j = 0; j < 16; ++j) {
        uint32_t d = src[j];
        e[j] = pk2h(__uint_as_float(d << 16), __uint_as_float(d & 0xffff0000u));
      }
    } else {
      const float* src = (const float*)x + goff;
#pragma unroll
      for (int j = 0; j < 16; ++j) e[j] = pk2h(src[2 * j], src[2 * j + 1]);
    }
    e[16] = 0;
    uint32_t* dn = (uint32_t*)(sxn + (size_t)i * 36);
    uint32_t* dsh = (uint32_t*)(sxs + (size_t)i * 36);
#pragma unroll
    for (int j = 0; j < 16; ++j) {
      dn[j] = e[j];
      dsh[j] = (e[j] >> 16) | (e[j + 1] << 16);
    }
  }

  // conv1 weight fragments (loop-invariant, per-lane pre-swizzled)
  h8v b1[3];
#pragma unroll
  for (int ic = 0; ic < 3; ++ic)
    b1[ic] = *(const h8v*)(cdh + ((size_t)ic * 64 + ln) * 8);
  const float bias1 = (mrow < 6) ? cb1f[mrow] : 0.f;
  int toff1[4];
#pragma unroll
  for (int p = 0; p < 4; ++p) {
    int t = quad * 8 + 2 * p;
    if (t >= 30) t = 24;        // zero-weight pair: duplicate a real read
    toff1[p] = (t / 6) * 30 + t;  // = ky*36 + kxp
  }
  const int qA = mrow >> 2, dyA = (mrow >> 1) & 1, dxA = mrow & 1;

  __syncthreads();

  // conv1 + relu + pool -> sp1 (f16, normal + shifted)
  const u16* c1base = dxA ? sxs : sxn;
  for (int tg = wv; tg < CIMG * 49; tg += 4) {
    int img = tg / 49, tau = tg - img * 49;
    int pqA = tau * 4 + qA;
    const u16* rb0 = c1base + (size_t)img * 3456 + lut1[pqA] + dyA * 36;
    f4v acc = {0.f, 0.f, 0.f, 0.f};
#pragma unroll
    for (int ic = 0; ic < 3; ++ic) {
      const u16* rb = rb0 + ic * 1152;
      union { uint32_t w[4]; h8v v; } au;
#pragma unroll
      for (int p = 0; p < 4; ++p)
        au.w[p] = *(const uint32_t*)(rb + toff1[p]);
      acc = __builtin_amdgcn_mfma_f32_16x16x32_f16(au.v, b1[ic], acc, 0, 0, 0);
    }
    float v = fmaxf(fmaxf(acc[0], acc[1]), fmaxf(acc[2], acc[3])) + bias1;
    v = fmaxf(v, 0.f);
    if (mrow < 6) {
      int pqC = tau * 4 + quad;
      int py = (pqC * 4682) >> 16, px = pqC - py * 14;
      int rbase = ((img * 6 + mrow) * 14 + py) * 18;
      u16 hv = f2h16(v);
      sp1n[rbase + px] = hv;
      sp1s[rbase + (px ? px - 1 : 17)] = hv;  // px=0 -> dump slot (never read)
    }
  }

  // conv2 weight fragments
  h8v b2[6];
#pragma unroll
  for (int ic = 0; ic < 6; ++ic)
    b2[ic] = *(const h8v*)(cdh + 1536 + ((size_t)ic * 64 + ln) * 8);
  const float bias2 = cb2f[mrow];
  int toff2[4];
#pragma unroll
  for (int p = 0; p < 4; ++p) {
    int t = quad * 8 + 2 * p;
    if (t >= 30) t = 24;
    toff2[p] = (t / 6) * 12 + t;  // = ky*18 + kxp
  }

  __syncthreads();

  // conv2 + relu + pool -> p2 (bf16)
  const u16* c2base = dxA ? sp1s : sp1n;
  for (int t2 = wv; t2 < 25; t2 += 4) {
    int PA = t2 * 4 + qA;
    int img = (PA * 41) >> 10, pq = PA - img * 25;
    const u16* rb0 = c2base + (size_t)img * 1512 + lut2[pq] + dyA * 18;
    f4v acc = {0.f, 0.f, 0.f, 0.f};
#pragma unroll
    for (int ic = 0; ic < 6; ++ic) {
      const u16* rb = rb0 + ic * 252;
      union { uint32_t w[4]; h8v v; } au;
#pragma unroll
      for (int p = 0; p < 4; ++p)
        au.w[p] = *(const uint32_t*)(rb + toff2[p]);
      acc = __builtin_amdgcn_mfma_f32_16x16x32_f16(au.v, b2[ic], acc, 0, 0, 0);
    }
    float v = fmaxf(fmaxf(acc[0], acc[1]), fmaxf(acc[2], acc[3])) + bias2;
    v = fmaxf(v, 0.f);
    int PC = t2 * 4 + quad;
    int imgc = (PC * 41) >> 10, pqc = PC - imgc * 25;
    if (gimg0 + imgc < Btot)
      p2[(gimg0 + imgc) * 416 + mrow * 25 + pqc] = f2bu(v);
  }

  for (int i = tid; i < CIMG * 16; i += 256) {
    int img = i / 16;
    if (gimg0 + img < Btot) p2[(gimg0 + img) * 416 + 400 + (i & 15)] = 0;
  }
}

// ---------------------------------------------------------------------------
// fcA: fc1 -> fc2 -> gate. 64 tokens/block; writes a2buf [B][104] bf16 +
// scbuf [B][2] f32. MFMA layouts as proven in R3.
// ---------------------------------------------------------------------------
template <bool INF32>
__global__ __launch_bounds__(256) void k_fcA(
    const int* __restrict__ flag,
    const u16* __restrict__ p2,
    const u16* __restrict__ fc1t, const u16* __restrict__ fc2t,
    const void* __restrict__ fc1b, const void* __restrict__ fc2b,
    const void* __restrict__ gw,
    u16* __restrict__ a2buf, float* __restrict__ scbuf) {
  if (*flag != (INF32 ? 1 : 0)) return;
  __shared__ __align__(16) char smem[62976];
  u16* a2s = (u16*)smem;                    // [64][104]
  u16* hs = (u16*)(smem + 13312);           // [64][136]
  u16* wbuf = (u16*)(smem + 31232);
  u16* xs = (u16*)(smem + 57856);           // [64][40]

  const int tid = threadIdx.x;
  const int wv = tid >> 6, ln = tid & 63;
  const int m = ln & 15, quad = ln >> 4;
  const long t0 = (long)blockIdx.x * 64;
  const int row0 = wv * 16 + quad * 4;

  for (int i = tid; i < 30720 / 4; i += 256) ((uint32_t*)smem)[i] = 0;

  // fc1
  f4v acc1[8];
#pragma unroll
  for (int i = 0; i < 8; ++i) acc1[i] = (f4v){0.f, 0.f, 0.f, 0.f};
  for (int s = 0; s < 13; ++s) {
    {
      int r = tid >> 2, c0 = (tid & 3) * 8;
      *(uint4*)(xs + r * 40 + c0) =
          *(const uint4*)(p2 + (t0 + r) * 416 + s * 32 + c0);
      int n = tid >> 1, cw = (tid & 1) * 16;
      *(uint4*)(wbuf + n * 40 + cw) = *(const uint4*)(fc1t + (long)n * 416 + s * 32 + cw);
      *(uint4*)(wbuf + n * 40 + cw + 8) =
          *(const uint4*)(fc1t + (long)n * 416 + s * 32 + cw + 8);
    }
    __syncthreads();
    s8v a = *(const s8v*)(xs + (wv * 16 + m) * 40 + quad * 8);
#pragma unroll
    for (int nt = 0; nt < 8; ++nt) {
      s8v b = *(const s8v*)(wbuf + (nt * 16 + m) * 40 + quad * 8);
      acc1[nt] = __builtin_amdgcn_mfma_f32_16x16x32_bf16(a, b, acc1[nt], 0, 0, 0);
    }
    __syncthreads();
  }
#pragma unroll
  for (int nt = 0; nt < 8; ++nt) {
    int n = nt * 16 + m;
    if (n < 120) {
      float bv = In<INF32>::ld(fc1b, n);
#pragma unroll
      for (int r = 0; r < 4; ++r)
        hs[(row0 + r) * 136 + n] = f2bu(fmaxf(acc1[nt][r] + bv, 0.f));
    }
  }
  __syncthreads();

  // fc2
  for (int i = tid; i < 1536; i += 256) {
    int n = i >> 4, c0 = (i & 15) * 8;
    *(uint4*)(wbuf + n * 136 + c0) = *(const uint4*)(fc2t + n * 128 + c0);
  }
  __syncthreads();
  f4v acc2[6];
#pragma unroll
  for (int i = 0; i < 6; ++i) acc2[i] = (f4v){0.f, 0.f, 0.f, 0.f};
  for (int s = 0; s < 4; ++s) {
    s8v a = *(const s8v*)(hs + (wv * 16 + m) * 136 + s * 32 + quad * 8);
#pragma unroll
    for (int nt = 0; nt < 6; ++nt) {
      s8v b = *(const s8v*)(wbuf + (nt * 16 + m) * 136 + s * 32 + quad * 8);
      acc2[nt] = __builtin_amdgcn_mfma_f32_16x16x32_bf16(a, b, acc2[nt], 0, 0, 0);
    }
  }
  __syncthreads();
#pragma unroll
  for (int nt = 0; nt < 6; ++nt) {
    int n = nt * 16 + m;
    if (n < 84) {
      float bv = In<INF32>::ld(fc2b, n);
#pragma unroll
      for (int r = 0; r < 4; ++r)
        a2s[(row0 + r) * 104 + n] = f2bu(fmaxf(acc2[nt][r] + bv, 0.f));
    }
  }
  __syncthreads();

  // gate + writeback
  if (tid < 64) {
    const u16* xr = a2s + tid * 104;
    float l0 = 0.f, l1 = 0.f;
    for (int k = 0; k < 84; ++k) {
      float xv = bu2f(xr[k]);
      l0 = fmaf(xv, In<INF32>::ld(gw, 2 * k), l0);
      l1 = fmaf(xv, In<INF32>::ld(gw, 2 * k + 1), l1);
    }
    float mx = fmaxf(l0, l1);
    float e0 = __expf(l0 - mx), e1 = __expf(l1 - mx);
    float inv = 1.f / (e0 + e1);
    *(float2*)(scbuf + (t0 + tid) * 2) = make_float2(e0 * inv, e1 * inv);
  }
  for (int i = tid; i < 832; i += 256) {  // 64 rows x 13 uint4
    int r = i / 13, c0 = (i - r * 13) * 8;
    *(uint4*)(a2buf + (t0 + r) * 104 + c0) = *(const uint4*)(a2s + r * 104 + c0);
  }
}

// ---------------------------------------------------------------------------
// exp: one expert per block (grid = [B/64, 2]) -> ybuf [2][B][96] f32.
// ---------------------------------------------------------------------------
template <bool INF32>
__global__ __launch_bounds__(256) void k_exp(
    const int* __restrict__ flag,
    const u16* __restrict__ a2buf, const float* __restrict__ scbuf,
    const u16* __restrict__ w1t, const u16* __restrict__ w2t,
    const void* __restrict__ eb1, const void* __restrict__ eb2,
    float* __restrict__ ybuf, int Btok) {
  if (*flag != (INF32 ? 1 : 0)) return;
  __shared__ __align__(16) char smem[57856];
  u16* a2s = (u16*)smem;                    // [64][104]
  u16* hs = (u16*)(smem + 13312);           // [64][136]
  u16* wbuf = (u16*)(smem + 30720);         // 26,624 B
  float* scs = (float*)(smem + 57344);      // [64]

  const int tid = threadIdx.x;
  const int wv = tid >> 6, ln = tid & 63;
  const int m = ln & 15, quad = ln >> 4;
  const int e = blockIdx.y;
  const long t0 = (long)blockIdx.x * 64;
  const int row0 = wv * 16 + quad * 4;
  const u16* w1te = w1t + (long)e * 196608;
  const u16* w2te = w2t + (long)e * 196608;

  for (int i = tid; i < 832; i += 256) {
    int r = i / 13, c0 = (i - r * 13) * 8;
    *(uint4*)(a2s + r * 104 + c0) = *(const uint4*)(a2buf + (t0 + r) * 104 + c0);
  }
  if (tid < 64) scs[tid] = scbuf[(t0 + tid) * 2 + e];
  __syncthreads();

  f4v acce[6];
#pragma unroll
  for (int i = 0; i < 6; ++i) acce[i] = (f4v){0.f, 0.f, 0.f, 0.f};
  for (int c = 0; c < 16; ++c) {
    const int n0 = c * 128;
    if (c) __syncthreads();
    for (int i = tid; i < 1536; i += 256) {  // wbuf[128][104] <- w1t chunk
      int nl = i / 12, c0 = (i - nl * 12) * 8;
      *(uint4*)(wbuf + nl * 104 + c0) =
          *(const uint4*)(w1te + (long)(n0 + nl) * 96 + c0);
    }
    __syncthreads();
    f4v acch[8];
#pragma unroll
    for (int i = 0; i < 8; ++i) acch[i] = (f4v){0.f, 0.f, 0.f, 0.f};
    for (int s = 0; s < 3; ++s) {
      s8v a = *(const s8v*)(a2s + (wv * 16 + m) * 104 + s * 32 + quad * 8);
#pragma unroll
      for (int nt = 0; nt < 8; ++nt) {
        s8v b = *(const s8v*)(wbuf + (nt * 16 + m) * 104 + s * 32 + quad * 8);
        acch[nt] = __builtin_amdgcn_mfma_f32_16x16x32_bf16(a, b, acch[nt], 0, 0, 0);
      }
    }
#pragma unroll
    for (int nt = 0; nt < 8; ++nt) {
      float bv = In<INF32>::ld(eb1, (long)e * 2048 + n0 + nt * 16 + m);
#pragma unroll
      for (int r = 0; r < 4; ++r)
        hs[(row0 + r) * 136 + nt * 16 + m] = f2bu(fmaxf(acch[nt][r] + bv, 0.f));
    }
    __syncthreads();
    for (int i = tid; i < 1536; i += 256) {  // wbuf[96][136] <- w2t slice
      int n = i >> 4, c0 = (i & 15) * 8;
      *(uint4*)(wbuf + n * 136 + c0) =
          *(const uint4*)(w2te + (long)n * 2048 + n0 + c0);
    }
    __syncthreads();
    for (int s = 0; s < 4; ++s) {
      s8v a = *(const s8v*)(hs + (wv * 16 + m) * 136 + s * 32 + quad * 8);
#pragma unroll
      for (int nt = 0; nt < 6; ++nt) {
        s8v b = *(const s8v*)(wbuf + (nt * 16 + m) * 136 + s * 32 + quad * 8);
        acce[nt] = __builtin_amdgcn_mfma_f32_16x16x32_bf16(a, b, acce[nt], 0, 0, 0);
      }
    }
  }

  // y_e = sc * (acce + b2) -> ybuf
#pragma unroll
  for (int nt = 0; nt < 6; ++nt) {
    int d = nt * 16 + m;
    float bv = (d < 84) ? In<INF32>::ld(eb2, (long)e * 84 + d) : 0.f;
#pragma unroll
    for (int r = 0; r < 4; ++r) {
      float sc = scs[row0 + r];
      ybuf[((size_t)e * Btok + t0 + row0 + r) * 96 + d] = sc * (acce[nt][r] + bv);
    }
  }
}

// ---------------------------------------------------------------------------
// fc3: out = (y0 + y1) @ w3 + b3. 64 tokens/block.
// ---------------------------------------------------------------------------
template <bool INF32>
__global__ __launch_bounds__(256) void k_fc3(
    const int* __restrict__ flag,
    const float* __restrict__ ybuf,
    const void* __restrict__ w3, const void* __restrict__ b3,
    void* __restrict__ out, int Btok) {
  if (*flag != (INF32 ? 1 : 0)) return;
  __shared__ float sw3[840];
  __shared__ float sb3[10];
  const int tid = threadIdx.x;
  const long t0 = (long)blockIdx.x * 64;
  for (int i = tid; i < 840; i += 256) sw3[i] = In<INF32>::ld(w3, i);
  if (tid < 10) sb3[tid] = In<INF32>::ld(b3, tid);
  __syncthreads();
  for (int idx = tid; idx < 640; idx += 256) {
    int tk = idx / 10, cc = idx - tk * 10;
    const float* y0r = ybuf + (t0 + tk) * 96;
    const float* y1r = ybuf + ((size_t)Btok + t0 + tk) * 96;
    float acc = sb3[cc];
    for (int d = 0; d < 84; ++d)
      acc = fmaf(y0r[d] + y1r[d], sw3[d * 10 + cc], acc);
    long oi = (t0 + tk) * 10 + cc;
    if (INF32) ((float*)out)[oi] = acc;
    else ((u16*)out)[oi] = f2bu(acc);
  }
}

// ---------------------------------------------------------------------------
extern "C" void kernel_launch(void* const* d_in, const int* in_sizes, int n_in,
                              void* d_out, int out_size, void* d_ws, size_t ws_size,
                              hipStream_t stream) {
  const int B = in_sizes[0] / 3072;  // 16384
  char* wsb = (char*)d_ws;
  int* flag = (int*)wsb;
  u16* p2 = (u16*)(wsb + 64);                    // [B][416] bf16
  u16* fc1t = p2 + (size_t)B * 416;              // 53,248 elems
  u16* fc2t = fc1t + 53248;                      // 12,288
  u16* w1t = fc2t + 12288;                       // 393,216
  u16* w2t = w1t + 393216;                       // 393,216
  uint32_t* cdw = (uint32_t*)(w2t + 393216);     // 2,326 dwords
  u16* a2buf = (u16*)(cdw + 2326);               // [B][104] bf16
  float* scbuf = (float*)(a2buf + (size_t)B * 104);  // [B][2] f32
  float* ybuf = scbuf + (size_t)B * 2;           // [2][B][96] f32

  k_detect<<<1, 64, 0, stream>>>((const u16*)d_in[0], flag);

  // 856,598 work items -> 3347 blocks (3346 was the R2 correctness bug:
  // the tail 22 items are the conv biases, which were never written).
  k_trans<false><<<3347, 256, 0, stream>>>(flag, d_in[5], d_in[7], d_in[10],
                                           d_in[12], d_in[1], d_in[2], d_in[3],
                                           d_in[4], fc1t, fc2t, w1t, w2t, cdw);
  k_trans<true><<<3347, 256, 0, stream>>>(flag, d_in[5], d_in[7], d_in[10],
                                          d_in[12], d_in[1], d_in[2], d_in[3],
                                          d_in[4], fc1t, fc2t, w1t, w2t, cdw);

  const int convGrid = (B + CIMG - 1) / CIMG;
  k_conv<false><<<convGrid, 256, 0, stream>>>(flag, d_in[0], cdw, p2, B);
  k_conv<true><<<convGrid, 256, 0, stream>>>(flag, d_in[0], cdw, p2, B);

  k_fcA<false><<<B / 64, 256, 0, stream>>>(flag, p2, fc1t, fc2t, d_in[6],
                                           d_in[8], d_in[9], a2buf, scbuf);
  k_fcA<true><<<B / 64, 256, 0, stream>>>(flag, p2, fc1t, fc2t, d_in[6],
                                          d_in[8], d_in[9], a2buf, scbuf);

  dim3 eg(B / 64, 2);
  k_exp<false><<<eg, 256, 0, stream>>>(flag, a2buf, scbuf, w1t, w2t, d_in[11],
                                       d_in[13], ybuf, B);
  k_exp<true><<<eg, 256, 0, stream>>>(flag, a2buf, scbuf, w1t, w2t, d_in[11],
                                      d_in[13], ybuf, B);

  k_fc3<false><<<B / 64, 256, 0, stream>>>(flag, ybuf, d_in[14], d_in[15],
                                           d_out, B);
  k_fc3<true><<<B / 64, 256, 0, stream>>>(flag, ybuf, d_in[14], d_in[15],
                                          d_out, B);
}

// Round 5
// 542.271 us; speedup vs baseline: 1.1455x; 1.0277x over previous
//
#include <hip/hip_runtime.h>
#include <stdint.h>

typedef unsigned short u16;
typedef __attribute__((ext_vector_type(8))) short s8v;    // 8 x bf16
typedef __attribute__((ext_vector_type(4))) float f4v;    // 4 x f32
typedef __fp16 h2v __attribute__((ext_vector_type(2)));   // 2 x f16
typedef __fp16 h8v __attribute__((ext_vector_type(8)));   // 8 x f16

__device__ __forceinline__ float bu2f(u16 u) {
  return __uint_as_float(((uint32_t)u) << 16);
}
__device__ __forceinline__ u16 f2bu(float f) {
  uint32_t u = __float_as_uint(f);
  u += 0x7fffu + ((u >> 16) & 1u);  // RNE
  return (u16)(u >> 16);
}

union U32H2 { uint32_t u; h2v h; };

__device__ __forceinline__ uint32_t pk2h(float a, float b) {
  U32H2 x;
  x.h = __builtin_amdgcn_cvt_pkrtz(a, b);  // exact for bf16-valued inputs
  return x.u;
}

// ---- input dtype abstraction ----------------------------------------------
template <bool F32> struct In;
template <> struct In<true> {
  static __device__ __forceinline__ float ld(const void* p, long i) {
    return ((const float*)p)[i];
  }
};
template <> struct In<false> {
  static __device__ __forceinline__ float ld(const void* p, long i) {
    return bu2f(((const u16*)p)[i]);
  }
};

// ---- dtype detector (proven) ----------------------------------------------
__global__ void k_detect(const u16* __restrict__ x, int* __restrict__ flag) {
  __shared__ int s[64];
  int cnt = 0;
  for (int i = threadIdx.x; i < 2048; i += 64) {
    int e = (x[i] >> 7) & 0xFF;
    cnt += (e >= 96 && e <= 134) ? 1 : 0;
  }
  s[threadIdx.x] = cnt;
  __syncthreads();
  if (threadIdx.x == 0) {
    int t = 0;
    for (int i = 0; i < 64; ++i) t += s[i];
    *flag = (t >= 1843) ? 0 : 1;  // 0 = bf16, 1 = f32
  }
}

// ---------------------------------------------------------------------------
// Weight transforms into ws:
//  fc1t [128][416] bf16, fc2t [96][128] bf16, w1t [2][2048][96] bf16,
//  w2t [2][96][2048] bf16,
//  cdw: MFMA conv weights: cd1m[3][64][8] f16, cd2m[6][64][8] f16,
//       cb1[6] f32 @dword 2304, cb2[16] f32 @dword 2310. Total 2326 dwords.
// Tap order for conv MFMA (row-padded to 6): t = quad*8 + j,
//   ky = t/6, kxp = t%6; weight 0 for kxp==5 or t>=30 (and n>=6 for conv1).
// ---------------------------------------------------------------------------
__device__ __forceinline__ u16 f2h16(float f) {
  __fp16 h = (__fp16)f;
  u16 r;
  __builtin_memcpy(&r, &h, 2);
  return r;
}

template <bool INF32>
__global__ __launch_bounds__(256) void k_trans(
    const int* __restrict__ flag,
    const void* __restrict__ fc1w, const void* __restrict__ fc2w,
    const void* __restrict__ ew1, const void* __restrict__ ew2,
    const void* __restrict__ c1w, const void* __restrict__ c1b,
    const void* __restrict__ c2w, const void* __restrict__ c2b,
    u16* __restrict__ fc1t, u16* __restrict__ fc2t,
    u16* __restrict__ w1t, u16* __restrict__ w2t,
    uint32_t* __restrict__ cdw) {
  if (*flag != (INF32 ? 1 : 0)) return;
  long gid = (long)blockIdx.x * 256 + threadIdx.x;
  if (gid < 53248) {                       // fc1t: [128 n][416 k]
    int n = (int)(gid / 416), k = (int)(gid % 416);
    fc1t[gid] = (n < 120 && k < 400) ? f2bu(In<INF32>::ld(fc1w, (long)k * 120 + n)) : (u16)0;
  } else if (gid < 65536) {                // fc2t: [96 n][128 k]
    long i = gid - 53248;
    int n = (int)(i / 128), k = (int)(i % 128);
    fc2t[i] = (n < 84 && k < 120) ? f2bu(In<INF32>::ld(fc2w, (long)k * 84 + n)) : (u16)0;
  } else if (gid < 458752) {               // w1t: [2][2048 n][96 k]
    long i = gid - 65536;
    int e = (int)(i / 196608);
    long r = i % 196608;
    int n = (int)(r / 96), k = (int)(r % 96);
    w1t[i] = (k < 84) ? f2bu(In<INF32>::ld(ew1, ((long)e * 84 + k) * 2048 + n)) : (u16)0;
  } else if (gid < 851968) {               // w2t: [2][96 n][2048 k]
    long i = gid - 458752;
    int e = (int)(i / 196608);
    long r = i % 196608;
    int n = (int)(r / 2048), k = (int)(r % 2048);
    w2t[i] = (n < 84) ? f2bu(In<INF32>::ld(ew2, ((long)e * 2048 + k) * 84 + n)) : (u16)0;
  } else if (gid < 856598) {               // conv MFMA weights + biases
    long i = gid - 851968;
    u16* cdh = (u16*)cdw;
    if (i < 1536) {          // cd1m [3 ic][64 lane][8 j]
      int ic = (int)(i >> 9);
      int r = (int)(i & 511);
      int lnn = r >> 3, j = r & 7;
      int n = lnn & 15, qd = lnn >> 4;
      int t = qd * 8 + j, ky = t / 6, kxp = t - ky * 6;
      float v = (n < 6 && t < 30 && kxp < 5)
          ? In<INF32>::ld(c1w, ((long)(n * 3 + ic) * 5 + ky) * 5 + kxp) : 0.f;
      cdh[i] = f2h16(v);
    } else if (i < 4608) {   // cd2m [6 ic][64 lane][8 j]
      long jj = i - 1536;
      int ic = (int)(jj >> 9);
      int r = (int)(jj & 511);
      int lnn = r >> 3, j = r & 7;
      int n = lnn & 15, qd = lnn >> 4;
      int t = qd * 8 + j, ky = t / 6, kxp = t - ky * 6;
      float v = (t < 30 && kxp < 5)
          ? In<INF32>::ld(c2w, ((long)(n * 6 + ic) * 5 + ky) * 5 + kxp) : 0.f;
      cdh[1536 + jj] = f2h16(v);
    } else if (i < 4614) {   // cb1 (f32)
      ((float*)(cdw + 2304))[i - 4608] = In<INF32>::ld(c1b, i - 4608);
    } else if (i < 4630) {   // cb2 (f32)
      ((float*)(cdw + 2310))[i - 4614] = In<INF32>::ld(c2b, i - 4614);
    }
  }
}

// ---------------------------------------------------------------------------
// Conv kernel v5: MFMA implicit-GEMM, occupancy + bank-stride tuned.
//   CIMG=2 and sx row stride 34 elems (68 B = 17 banks, odd -> conflict-free
//   period 32) cut LDS to ~38.7 KB -> 4 blocks/CU (16 waves/CU), vs v4's
//   2 blocks/CU at stride 36 (18 banks, even -> 4-way write conflicts).
// Out p2: [B][416] bf16, cols 400..415 zero.
// ---------------------------------------------------------------------------
#define CIMG 2
#define XSTR 34           // sx row stride (elems); max col read = 31
#define PSTR 18           // sp1 row stride (elems); 9-bank odd stride
template <bool INF32>
__global__ __launch_bounds__(256) void k_conv(
    const int* __restrict__ flag,
    const void* __restrict__ x,
    const uint32_t* __restrict__ cdw,
    u16* __restrict__ p2, int Btot) {
  if (*flag != (INF32 ? 1 : 0)) return;
  __shared__ __align__(16) u16 sxn[CIMG * 3 * 32 * XSTR];   // 13,056 B
  __shared__ __align__(16) u16 sxs[CIMG * 3 * 32 * XSTR];   // shifted copy
  __shared__ __align__(16) u16 sp1n[CIMG * 6 * 14 * PSTR];  // 6,048 B
  __shared__ __align__(16) u16 sp1s[CIMG * 6 * 14 * PSTR];
  __shared__ u16 lut1[196];
  __shared__ u16 lut2[32];
  const u16* cdh = (const u16*)cdw;
  const float* cb1f = (const float*)(cdw + 2304);
  const float* cb2f = (const float*)(cdw + 2310);
  const int tid = threadIdx.x;
  const int wv = tid >> 6, ln = tid & 63;
  const int mrow = ln & 15, quad = ln >> 4;
  const long gimg0 = (long)blockIdx.x * CIMG;

  // pooled-pos -> element-offset LUTs
  if (tid < 196) {
    int py = tid / 14, px = tid - py * 14;
    lut1[tid] = (u16)((2 * py) * XSTR + 2 * px);
  } else if (tid < 228) {
    int i = tid - 196;
    if (i < 25) {
      int py = i / 5, px = i - py * 5;
      lut2[i] = (u16)((2 * py) * PSTR + 2 * px);
    }
  }
  // zero sp1s elts 12,13 of each row (elt13 = orig col14 pad, read by conv2)
  for (int r = tid; r < CIMG * 6 * 14; r += 256)
    *(uint32_t*)(sp1s + (size_t)r * PSTR + 12) = 0;

  // stage x -> f16 LDS (normal + shifted copies); cols 32..33 never read
  for (int i = tid; i < CIMG * 96; i += 256) {
    int img = i / 96;
    if (gimg0 + img >= Btot) continue;
    int rem = i - img * 96;
    long goff = (gimg0 + img) * 3072 + (long)rem * 32;
    uint32_t e[17];
    if (!INF32) {
      const uint32_t* src = (const uint32_t*)((const u16*)x + goff);
#pragma unroll
      for (int j = 0; j < 16; ++j) {
        uint32_t d = src[j];
        e[j] = pk2h(__uint_as_float(d << 16), __uint_as_float(d & 0xffff0000u));
      }
    } else {
      const float* src = (const float*)x + goff;
#pragma unroll
      for (int j = 0; j < 16; ++j) e[j] = pk2h(src[2 * j], src[2 * j + 1]);
    }
    e[16] = 0;
    uint32_t* dn = (uint32_t*)(sxn + (size_t)i * XSTR);
    uint32_t* dsh = (uint32_t*)(sxs + (size_t)i * XSTR);
#pragma unroll
    for (int j = 0; j < 16; ++j) {
      dn[j] = e[j];
      dsh[j] = (e[j] >> 16) | (e[j + 1] << 16);
    }
  }

  // conv1 weight fragments (loop-invariant, per-lane pre-swizzled)
  h8v b1[3];
#pragma unroll
  for (int ic = 0; ic < 3; ++ic)
    b1[ic] = *(const h8v*)(cdh + ((size_t)ic * 64 + ln) * 8);
  const float bias1 = (mrow < 6) ? cb1f[mrow] : 0.f;
  int toff1[4];
#pragma unroll
  for (int p = 0; p < 4; ++p) {
    int t = quad * 8 + 2 * p;
    if (t >= 30) t = 24;          // zero-weight pair: duplicate a real read
    toff1[p] = (t / 6) * (XSTR - 6) + t;  // = ky*XSTR + kxp
  }
  const int qA = mrow >> 2, dyA = (mrow >> 1) & 1, dxA = mrow & 1;

  __syncthreads();

  // conv1 + relu + pool -> sp1 (f16, normal + shifted)
  const u16* c1base = dxA ? sxs : sxn;
  for (int tg = wv; tg < CIMG * 49; tg += 4) {
    int img = tg / 49, tau = tg - img * 49;
    int pqA = tau * 4 + qA;
    const u16* rb0 = c1base + (size_t)img * (3 * 32 * XSTR) + lut1[pqA] + dyA * XSTR;
    f4v acc = {0.f, 0.f, 0.f, 0.f};
#pragma unroll
    for (int ic = 0; ic < 3; ++ic) {
      const u16* rb = rb0 + ic * (32 * XSTR);
      union { uint32_t w[4]; h8v v; } au;
#pragma unroll
      for (int p = 0; p < 4; ++p)
        au.w[p] = *(const uint32_t*)(rb + toff1[p]);
      acc = __builtin_amdgcn_mfma_f32_16x16x32_f16(au.v, b1[ic], acc, 0, 0, 0);
    }
    float v = fmaxf(fmaxf(acc[0], acc[1]), fmaxf(acc[2], acc[3])) + bias1;
    v = fmaxf(v, 0.f);
    if (mrow < 6) {
      int pqC = tau * 4 + quad;
      int py = (pqC * 4682) >> 16, px = pqC - py * 14;
      int rbase = ((img * 6 + mrow) * 14 + py) * PSTR;
      u16 hv = f2h16(v);
      sp1n[rbase + px] = hv;
      sp1s[rbase + (px ? px - 1 : PSTR - 1)] = hv;  // px=0 -> dump slot
    }
  }

  // conv2 weight fragments
  h8v b2[6];
#pragma unroll
  for (int ic = 0; ic < 6; ++ic)
    b2[ic] = *(const h8v*)(cdh + 1536 + ((size_t)ic * 64 + ln) * 8);
  const float bias2 = cb2f[mrow];
  int toff2[4];
#pragma unroll
  for (int p = 0; p < 4; ++p) {
    int t = quad * 8 + 2 * p;
    if (t >= 30) t = 24;
    toff2[p] = (t / 6) * (PSTR - 6) + t;  // = ky*PSTR + kxp
  }

  __syncthreads();

  // conv2 + relu + pool -> p2 (bf16). NP2=50 positions = 12.5 MFMA tiles:
  // last tile clamps its A-rows and guards the C-write (MFMA is whole-wave).
  const int NP2 = CIMG * 25;
  const u16* c2base = dxA ? sp1s : sp1n;
  for (int t2 = wv; t2 * 4 < NP2; t2 += 4) {
    int PA = t2 * 4 + qA;
    if (PA >= NP2) PA = NP2 - 1;
    int img = (PA * 41) >> 10, pq = PA - img * 25;
    const u16* rb0 = c2base + (size_t)img * (6 * 14 * PSTR) + lut2[pq] + dyA * PSTR;
    f4v acc = {0.f, 0.f, 0.f, 0.f};
#pragma unroll
    for (int ic = 0; ic < 6; ++ic) {
      const u16* rb = rb0 + ic * (14 * PSTR);
      union { uint32_t w[4]; h8v v; } au;
#pragma unroll
      for (int p = 0; p < 4; ++p)
        au.w[p] = *(const uint32_t*)(rb + toff2[p]);
      acc = __builtin_amdgcn_mfma_f32_16x16x32_f16(au.v, b2[ic], acc, 0, 0, 0);
    }
    float v = fmaxf(fmaxf(acc[0], acc[1]), fmaxf(acc[2], acc[3])) + bias2;
    v = fmaxf(v, 0.f);
    int PC = t2 * 4 + quad;
    if (PC < NP2) {
      int imgc = (PC * 41) >> 10, pqc = PC - imgc * 25;
      if (gimg0 + imgc < Btot)
        p2[(gimg0 + imgc) * 416 + mrow * 25 + pqc] = f2bu(v);
    }
  }

  for (int i = tid; i < CIMG * 16; i += 256) {
    int img = i / 16;
    if (gimg0 + img < Btot) p2[(gimg0 + img) * 416 + 400 + (i & 15)] = 0;
  }
}

// ---------------------------------------------------------------------------
// fcA: fc1 -> fc2 -> gate. 64 tokens/block; writes a2buf [B][104] bf16 +
// scbuf [B][2] f32. MFMA layouts as proven in R3.
// ---------------------------------------------------------------------------
template <bool INF32>
__global__ __launch_bounds__(256) void k_fcA(
    const int* __restrict__ flag,
    const u16* __restrict__ p2,
    const u16* __restrict__ fc1t, const u16* __restrict__ fc2t,
    const void* __restrict__ fc1b, const void* __restrict__ fc2b,
    const void* __restrict__ gw,
    u16* __restrict__ a2buf, float* __restrict__ scbuf) {
  if (*flag != (INF32 ? 1 : 0)) return;
  __shared__ __align__(16) char smem[62976];
  u16* a2s = (u16*)smem;                    // [64][104]
  u16* hs = (u16*)(smem + 13312);           // [64][136]
  u16* wbuf = (u16*)(smem + 31232);
  u16* xs = (u16*)(smem + 57856);           // [64][40]

  const int tid = threadIdx.x;
  const int wv = tid >> 6, ln = tid & 63;
  const int m = ln & 15, quad = ln >> 4;
  const long t0 = (long)blockIdx.x * 64;
  const int row0 = wv * 16 + quad * 4;

  for (int i = tid; i < 30720 / 4; i += 256) ((uint32_t*)smem)[i] = 0;

  // fc1
  f4v acc1[8];
#pragma unroll
  for (int i = 0; i < 8; ++i) acc1[i] = (f4v){0.f, 0.f, 0.f, 0.f};
  for (int s = 0; s < 13; ++s) {
    {
      int r = tid >> 2, c0 = (tid & 3) * 8;
      *(uint4*)(xs + r * 40 + c0) =
          *(const uint4*)(p2 + (t0 + r) * 416 + s * 32 + c0);
      int n = tid >> 1, cw = (tid & 1) * 16;
      *(uint4*)(wbuf + n * 40 + cw) = *(const uint4*)(fc1t + (long)n * 416 + s * 32 + cw);
      *(uint4*)(wbuf + n * 40 + cw + 8) =
          *(const uint4*)(fc1t + (long)n * 416 + s * 32 + cw + 8);
    }
    __syncthreads();
    s8v a = *(const s8v*)(xs + (wv * 16 + m) * 40 + quad * 8);
#pragma unroll
    for (int nt = 0; nt < 8; ++nt) {
      s8v b = *(const s8v*)(wbuf + (nt * 16 + m) * 40 + quad * 8);
      acc1[nt] = __builtin_amdgcn_mfma_f32_16x16x32_bf16(a, b, acc1[nt], 0, 0, 0);
    }
    __syncthreads();
  }
#pragma unroll
  for (int nt = 0; nt < 8; ++nt) {
    int n = nt * 16 + m;
    if (n < 120) {
      float bv = In<INF32>::ld(fc1b, n);
#pragma unroll
      for (int r = 0; r < 4; ++r)
        hs[(row0 + r) * 136 + n] = f2bu(fmaxf(acc1[nt][r] + bv, 0.f));
    }
  }
  __syncthreads();

  // fc2
  for (int i = tid; i < 1536; i += 256) {
    int n = i >> 4, c0 = (i & 15) * 8;
    *(uint4*)(wbuf + n * 136 + c0) = *(const uint4*)(fc2t + n * 128 + c0);
  }
  __syncthreads();
  f4v acc2[6];
#pragma unroll
  for (int i = 0; i < 6; ++i) acc2[i] = (f4v){0.f, 0.f, 0.f, 0.f};
  for (int s = 0; s < 4; ++s) {
    s8v a = *(const s8v*)(hs + (wv * 16 + m) * 136 + s * 32 + quad * 8);
#pragma unroll
    for (int nt = 0; nt < 6; ++nt) {
      s8v b = *(const s8v*)(wbuf + (nt * 16 + m) * 136 + s * 32 + quad * 8);
      acc2[nt] = __builtin_amdgcn_mfma_f32_16x16x32_bf16(a, b, acc2[nt], 0, 0, 0);
    }
  }
  __syncthreads();
#pragma unroll
  for (int nt = 0; nt < 6; ++nt) {
    int n = nt * 16 + m;
    if (n < 84) {
      float bv = In<INF32>::ld(fc2b, n);
#pragma unroll
      for (int r = 0; r < 4; ++r)
        a2s[(row0 + r) * 104 + n] = f2bu(fmaxf(acc2[nt][r] + bv, 0.f));
    }
  }
  __syncthreads();

  // gate + writeback
  if (tid < 64) {
    const u16* xr = a2s + tid * 104;
    float l0 = 0.f, l1 = 0.f;
    for (int k = 0; k < 84; ++k) {
      float xv = bu2f(xr[k]);
      l0 = fmaf(xv, In<INF32>::ld(gw, 2 * k), l0);
      l1 = fmaf(xv, In<INF32>::ld(gw, 2 * k + 1), l1);
    }
    float mx = fmaxf(l0, l1);
    float e0 = __expf(l0 - mx), e1 = __expf(l1 - mx);
    float inv = 1.f / (e0 + e1);
    *(float2*)(scbuf + (t0 + tid) * 2) = make_float2(e0 * inv, e1 * inv);
  }
  for (int i = tid; i < 832; i += 256) {  // 64 rows x 13 uint4
    int r = i / 13, c0 = (i - r * 13) * 8;
    *(uint4*)(a2buf + (t0 + r) * 104 + c0) = *(const uint4*)(a2s + r * 104 + c0);
  }
}

// ---------------------------------------------------------------------------
// exp: one expert per block (grid = [B/64, 2]) -> ybuf [2][B][96] f32.
// ---------------------------------------------------------------------------
template <bool INF32>
__global__ __launch_bounds__(256) void k_exp(
    const int* __restrict__ flag,
    const u16* __restrict__ a2buf, const float* __restrict__ scbuf,
    const u16* __restrict__ w1t, const u16* __restrict__ w2t,
    const void* __restrict__ eb1, const void* __restrict__ eb2,
    float* __restrict__ ybuf, int Btok) {
  if (*flag != (INF32 ? 1 : 0)) return;
  __shared__ __align__(16) char smem[57856];
  u16* a2s = (u16*)smem;                    // [64][104]
  u16* hs = (u16*)(smem + 13312);           // [64][136]
  u16* wbuf = (u16*)(smem + 30720);         // 26,624 B
  float* scs = (float*)(smem + 57344);      // [64]

  const int tid = threadIdx.x;
  const int wv = tid >> 6, ln = tid & 63;
  const int m = ln & 15, quad = ln >> 4;
  const int e = blockIdx.y;
  const long t0 = (long)blockIdx.x * 64;
  const int row0 = wv * 16 + quad * 4;
  const u16* w1te = w1t + (long)e * 196608;
  const u16* w2te = w2t + (long)e * 196608;

  for (int i = tid; i < 832; i += 256) {
    int r = i / 13, c0 = (i - r * 13) * 8;
    *(uint4*)(a2s + r * 104 + c0) = *(const uint4*)(a2buf + (t0 + r) * 104 + c0);
  }
  if (tid < 64) scs[tid] = scbuf[(t0 + tid) * 2 + e];
  __syncthreads();

  f4v acce[6];
#pragma unroll
  for (int i = 0; i < 6; ++i) acce[i] = (f4v){0.f, 0.f, 0.f, 0.f};
  for (int c = 0; c < 16; ++c) {
    const int n0 = c * 128;
    if (c) __syncthreads();
    for (int i = tid; i < 1536; i += 256) {  // wbuf[128][104] <- w1t chunk
      int nl = i / 12, c0 = (i - nl * 12) * 8;
      *(uint4*)(wbuf + nl * 104 + c0) =
          *(const uint4*)(w1te + (long)(n0 + nl) * 96 + c0);
    }
    __syncthreads();
    f4v acch[8];
#pragma unroll
    for (int i = 0; i < 8; ++i) acch[i] = (f4v){0.f, 0.f, 0.f, 0.f};
    for (int s = 0; s < 3; ++s) {
      s8v a = *(const s8v*)(a2s + (wv * 16 + m) * 104 + s * 32 + quad * 8);
#pragma unroll
      for (int nt = 0; nt < 8; ++nt) {
        s8v b = *(const s8v*)(wbuf + (nt * 16 + m) * 104 + s * 32 + quad * 8);
        acch[nt] = __builtin_amdgcn_mfma_f32_16x16x32_bf16(a, b, acch[nt], 0, 0, 0);
      }
    }
#pragma unroll
    for (int nt = 0; nt < 8; ++nt) {
      float bv = In<INF32>::ld(eb1, (long)e * 2048 + n0 + nt * 16 + m);
#pragma unroll
      for (int r = 0; r < 4; ++r)
        hs[(row0 + r) * 136 + nt * 16 + m] = f2bu(fmaxf(acch[nt][r] + bv, 0.f));
    }
    __syncthreads();
    for (int i = tid; i < 1536; i += 256) {  // wbuf[96][136] <- w2t slice
      int n = i >> 4, c0 = (i & 15) * 8;
      *(uint4*)(wbuf + n * 136 + c0) =
          *(const uint4*)(w2te + (long)n * 2048 + n0 + c0);
    }
    __syncthreads();
    for (int s = 0; s < 4; ++s) {
      s8v a = *(const s8v*)(hs + (wv * 16 + m) * 136 + s * 32 + quad * 8);
#pragma unroll
      for (int nt = 0; nt < 6; ++nt) {
        s8v b = *(const s8v*)(wbuf + (nt * 16 + m) * 136 + s * 32 + quad * 8);
        acce[nt] = __builtin_amdgcn_mfma_f32_16x16x32_bf16(a, b, acce[nt], 0, 0, 0);
      }
    }
  }

  // y_e = sc * (acce + b2) -> ybuf
#pragma unroll
  for (int nt = 0; nt < 6; ++nt) {
    int d = nt * 16 + m;
    float bv = (d < 84) ? In<INF32>::ld(eb2, (long)e * 84 + d) : 0.f;
#pragma unroll
    for (int r = 0; r < 4; ++r) {
      float sc = scs[row0 + r];
      ybuf[((size_t)e * Btok + t0 + row0 + r) * 96 + d] = sc * (acce[nt][r] + bv);
    }
  }
}

// ---------------------------------------------------------------------------
// fc3: out = (y0 + y1) @ w3 + b3. 64 tokens/block.
// ---------------------------------------------------------------------------
template <bool INF32>
__global__ __launch_bounds__(256) void k_fc3(
    const int* __restrict__ flag,
    const float* __restrict__ ybuf,
    const void* __restrict__ w3, const void* __restrict__ b3,
    void* __restrict__ out, int Btok) {
  if (*flag != (INF32 ? 1 : 0)) return;
  __shared__ float sw3[840];
  __shared__ float sb3[10];
  const int tid = threadIdx.x;
  const long t0 = (long)blockIdx.x * 64;
  for (int i = tid; i < 840; i += 256) sw3[i] = In<INF32>::ld(w3, i);
  if (tid < 10) sb3[tid] = In<INF32>::ld(b3, tid);
  __syncthreads();
  for (int idx = tid; idx < 640; idx += 256) {
    int tk = idx / 10, cc = idx - tk * 10;
    const float* y0r = ybuf + (t0 + tk) * 96;
    const float* y1r = ybuf + ((size_t)Btok + t0 + tk) * 96;
    float acc = sb3[cc];
    for (int d = 0; d < 84; ++d)
      acc = fmaf(y0r[d] + y1r[d], sw3[d * 10 + cc], acc);
    long oi = (t0 + tk) * 10 + cc;
    if (INF32) ((float*)out)[oi] = acc;
    else ((u16*)out)[oi] = f2bu(acc);
  }
}

// ---------------------------------------------------------------------------
extern "C" void kernel_launch(void* const* d_in, const int* in_sizes, int n_in,
                              void* d_out, int out_size, void* d_ws, size_t ws_size,
                              hipStream_t stream) {
  const int B = in_sizes[0] / 3072;  // 16384
  char* wsb = (char*)d_ws;
  int* flag = (int*)wsb;
  u16* p2 = (u16*)(wsb + 64);                    // [B][416] bf16
  u16* fc1t = p2 + (size_t)B * 416;              // 53,248 elems
  u16* fc2t = fc1t + 53248;                      // 12,288
  u16* w1t = fc2t + 12288;                       // 393,216
  u16* w2t = w1t + 393216;                       // 393,216
  uint32_t* cdw = (uint32_t*)(w2t + 393216);     // 2,326 dwords
  u16* a2buf = (u16*)(cdw + 2326);               // [B][104] bf16
  float* scbuf = (float*)(a2buf + (size_t)B * 104);  // [B][2] f32
  float* ybuf = scbuf + (size_t)B * 2;           // [2][B][96] f32

  k_detect<<<1, 64, 0, stream>>>((const u16*)d_in[0], flag);

  // 856,598 work items -> 3347 blocks (tail 22 items are the conv biases).
  k_trans<false><<<3347, 256, 0, stream>>>(flag, d_in[5], d_in[7], d_in[10],
                                           d_in[12], d_in[1], d_in[2], d_in[3],
                                           d_in[4], fc1t, fc2t, w1t, w2t, cdw);
  k_trans<true><<<3347, 256, 0, stream>>>(flag, d_in[5], d_in[7], d_in[10],
                                          d_in[12], d_in[1], d_in[2], d_in[3],
                                          d_in[4], fc1t, fc2t, w1t, w2t, cdw);

  const int convGrid = (B + CIMG - 1) / CIMG;
  k_conv<false><<<convGrid, 256, 0, stream>>>(flag, d_in[0], cdw, p2, B);
  k_conv<true><<<convGrid, 256, 0, stream>>>(flag, d_in[0], cdw, p2, B);

  k_fcA<false><<<B / 64, 256, 0, stream>>>(flag, p2, fc1t, fc2t, d_in[6],
                                           d_in[8], d_in[9], a2buf, scbuf);
  k_fcA<true><<<B / 64, 256, 0, stream>>>(flag, p2, fc1t, fc2t, d_in[6],
                                          d_in[8], d_in[9], a2buf, scbuf);

  dim3 eg(B / 64, 2);
  k_exp<false><<<eg, 256, 0, stream>>>(flag, a2buf, scbuf, w1t, w2t, d_in[11],
                                       d_in[13], ybuf, B);
  k_exp<true><<<eg, 256, 0, stream>>>(flag, a2buf, scbuf, w1t, w2t, d_in[11],
                                      d_in[13], ybuf, B);

  k_fc3<false><<<B / 64, 256, 0, stream>>>(flag, ybuf, d_in[14], d_in[15],
                                           d_out, B);
  k_fc3<true><<<B / 64, 256, 0, stream>>>(flag, ybuf, d_in[14], d_in[15],
                                          d_out, B);
}